// Round 3
// baseline (481.133 us; speedup 1.0000x reference)
//
#include <hip/hip_runtime.h>
#include <cstdint>
#include <cstddef>

typedef _Float16 half8 __attribute__((ext_vector_type(8)));
typedef _Float16 half4 __attribute__((ext_vector_type(4)));
typedef float f32x4 __attribute__((ext_vector_type(4)));

// async global->LDS, 16B per lane; LDS dest must be wave-uniform base + lane*16
#define GLDS16(g, l) __builtin_amdgcn_global_load_lds( \
    (__attribute__((address_space(1))) void*)(g), \
    (__attribute__((address_space(3))) void*)(l), 16, 0, 0)

// raw barrier preceded by LDS-drain only (global stores stay in flight)
#define LBAR() do { asm volatile("s_waitcnt lgkmcnt(0)" ::: "memory"); \
                    __builtin_amdgcn_s_barrier(); } while (0)

// phase boilerplate: pin reads+staging before barrier, MFMA cluster after
#define PH_MID() do { __builtin_amdgcn_sched_barrier(0); \
                      __builtin_amdgcn_s_barrier(); \
                      __builtin_amdgcn_sched_barrier(0); \
                      __builtin_amdgcn_s_setprio(1); } while (0)
#define PH_END() do { __builtin_amdgcn_s_setprio(0); \
                      __builtin_amdgcn_sched_barrier(0); \
                      __builtin_amdgcn_s_barrier(); } while (0)

// ---------------------------------------------------------------------------
// fp32 -> fp16 convert
// ---------------------------------------------------------------------------
__global__ __launch_bounds__(256) void cvt_f32_f16(const float* __restrict__ src,
                                                   _Float16* __restrict__ dst, int n) {
  int i = (blockIdx.x * 256 + threadIdx.x) * 8;
  if (i >= n) return;
  float4 a = *(const float4*)(src + i);
  float4 b = *(const float4*)(src + i + 4);
  half8 h;
  h[0] = (_Float16)a.x; h[1] = (_Float16)a.y; h[2] = (_Float16)a.z; h[3] = (_Float16)a.w;
  h[4] = (_Float16)b.x; h[5] = (_Float16)b.y; h[6] = (_Float16)b.z; h[7] = (_Float16)b.w;
  *(half8*)(dst + i) = h;
}

// ---------------------------------------------------------------------------
// GEMM C[m,n] = sum_k A[m,k]*Bw[n,k] (+bias).  A fp16 MxK, Bw fp16 NxK, K=512.
// 256x256 tile, BK=64, 8 waves (2M x 4N), wave tile 128x64, 8-phase schedule
// (m201 template): each K-tile = 4 phases, each phase = {ds_read subtile ||
// stage 1 half-tile -> barrier -> setprio(1) 16 MFMA setprio(0) -> barrier}.
// Counted vmcnt(4) ONCE per K-tile (at q3) -- staging loads stay in flight
// across barriers; reads of K-tile c+1 need exactly the 4 half-tiles that
// vmcnt(4) retires.
//
// LDS: S[2][A|B][256x64] fragment-order, 128 KB, 1 block/CU, 2 waves/SIMD.
// Fragment order: band (16 rows) x 8 chunks of 8 halves; slot (r,c)=c*16+r,
// so both global_load_lds writes and ds_read_b128 are base + lane*16.
//
// Staging ledger (half-iter c, buffer p=c&1):   region's last read:
//   q0: A0(c+1) -> S[p^1]   A-half0 of p^1 last read (c-1,q2)  [2 bars prior]
//   q1: A1(c+1) -> S[p^1]   A-half1 same
//   q2: B0(c+2) -> S[p]     B of p last read this half-iter q1 [1 bar prior]
//   q3: B1(c+2) -> S[p]
// vmcnt(4) at (c,q3) retires {A0,A1(c+1),B0,B1(c+1)}, leaves {B0,B1(c+2)}.
// ---------------------------------------------------------------------------
template<int NOUT, int NT, bool BIAS>
__global__ __launch_bounds__(512, 2) void gemm_bt(const _Float16* __restrict__ A,
                                                  const _Float16* __restrict__ Bw,
                                                  const float* __restrict__ bias,
                                                  void* __restrict__ Cout) {
  constexpr int K = 512;
  __shared__ union {
    _Float16 S[2][2][16384];       // [buf parity][A=0/B=1][256x64 fragment-order]
    float E[2][16][264];           // epilogue staging
  } u;
  const int id  = blockIdx.x;
  const int xcd = id & 7;                 // XCD cohort: N-tiles of a band share L2
  const int jj  = id >> 3;
  const int by  = (jj / NT) * 8 + xcd;
  const int bx  = jj % NT;
  const int m_base = by * 256, n_base = bx * 256;

  const int t    = threadIdx.x;    // 0..511
  const int lane = t & 63;
  const int wid  = t >> 6;         // 0..7
  const int wm   = wid & 1;        // M half: rows wm*128..+127
  const int wn   = wid >> 1;       // N quarter: cols wn*64..+63
  const int cl   = lane & 15, q = lane >> 4;

  f32x4 acc[8][4] = {};

  // staging: slot s (0..2047): row=(s>>7)*16+(s&15), chunk c=(s>>4)&7.
  // thread t covers slots h*1024+t and h*1024+t+512 (same chunk, row+64).
  const int r0 = ((t >> 7) << 4) | (t & 15);
  const int c0 = (t >> 4) & 7;
  const _Float16* aR = A  + (size_t)(m_base + r0) * K + c0 * 8;
  const _Float16* bR = Bw + (size_t)(n_base + r0) * K + c0 * 8;
  char* Sb = (char*)&u.S[0][0][0];   // p stride 65536 B, mat stride 32768 B

  auto stageA = [&](int p, int h, int kt) {
    char* dst = Sb + p * 65536 + h * 16384 + t * 16;
    const _Float16* s = aR + (size_t)(h * 128) * K + kt * 64;
    GLDS16(s, dst);
    GLDS16(s + (size_t)64 * K, dst + 8192);
  };
  auto stageB = [&](int p, int h, int kt) {
    char* dst = Sb + p * 65536 + 32768 + h * 16384 + t * 16;
    const _Float16* s = bR + (size_t)(h * 128) * K + kt * 64;
    GLDS16(s, dst);
    GLDS16(s + (size_t)64 * K, dst + 8192);
  };

#define QUAD(AM, BN, BF) \
  _Pragma("unroll") for (int i_ = 0; i_ < 4; ++i_) \
  _Pragma("unroll") for (int j_ = 0; j_ < 2; ++j_) \
  _Pragma("unroll") for (int kk_ = 0; kk_ < 2; ++kk_) \
    acc[(AM)*4 + i_][(BN)*2 + j_] = __builtin_amdgcn_mfma_f32_16x16x32_f16( \
        af[i_][kk_], BF[j_][kk_], acc[(AM)*4 + i_][(BN)*2 + j_], 0, 0, 0);

  // prologue: K-tile 0 fully + B halves of K-tile 1; keep B(1) in flight
  stageA(0, 0, 0); stageA(0, 1, 0); stageB(0, 0, 0); stageB(0, 1, 0);
  stageB(1, 0, 1); stageB(1, 1, 1);
  asm volatile("s_waitcnt vmcnt(4)" ::: "memory");
  __builtin_amdgcn_s_barrier();

  half8 af[4][2], bf0[2][2], bf1[2][2];
#pragma unroll
  for (int c = 0; c < 8; ++c) {
    const int p = c & 1;
    const char* aB = (const char*)u.S[p][0] + wm * 16384 + lane * 16;
    const char* bB = (const char*)u.S[p][1] + wn * 8192 + lane * 16;

    // ---- q0: read af0 + bf0, stage A0(c+1), MFMA quad (0,0) ----
#pragma unroll
    for (int fm = 0; fm < 4; ++fm)
#pragma unroll
      for (int kk = 0; kk < 2; ++kk)
        af[fm][kk] = *(const half8*)(aB + fm * 2048 + kk * 1024);
#pragma unroll
    for (int fn = 0; fn < 2; ++fn)
#pragma unroll
      for (int kk = 0; kk < 2; ++kk)
        bf0[fn][kk] = *(const half8*)(bB + fn * 2048 + kk * 1024);
    if (c + 1 < 8) stageA(p ^ 1, 0, c + 1);
    PH_MID();
    QUAD(0, 0, bf0);
    PH_END();

    // ---- q1: read bf1, stage A1(c+1), MFMA quad (0,1) ----
#pragma unroll
    for (int fn = 0; fn < 2; ++fn)
#pragma unroll
      for (int kk = 0; kk < 2; ++kk)
        bf1[fn][kk] = *(const half8*)(bB + (2 + fn) * 2048 + kk * 1024);
    if (c + 1 < 8) stageA(p ^ 1, 1, c + 1);
    PH_MID();
    QUAD(0, 1, bf1);
    PH_END();

    // ---- q2: read af1 (reuse af regs), stage B0(c+2), MFMA quad (1,1) ----
#pragma unroll
    for (int fm = 0; fm < 4; ++fm)
#pragma unroll
      for (int kk = 0; kk < 2; ++kk)
        af[fm][kk] = *(const half8*)(aB + (4 + fm) * 2048 + kk * 1024);
    if (c + 2 < 8) stageB(p, 0, c + 2);
    PH_MID();
    QUAD(1, 1, bf1);
    PH_END();

    // ---- q3: stage B1(c+2), MFMA quad (1,0), K-tile-boundary vmcnt ----
    if (c + 2 < 8) stageB(p, 1, c + 2);
    PH_MID();
    QUAD(1, 0, bf0);
    __builtin_amdgcn_s_setprio(0);
    __builtin_amdgcn_sched_barrier(0);
    if (c < 6)       { asm volatile("s_waitcnt vmcnt(4)" ::: "memory"); }
    else if (c == 6) { asm volatile("s_waitcnt vmcnt(0)" ::: "memory"); }
    __builtin_amdgcn_s_barrier();
  }
#undef QUAD

  // epilogue: C/D layout (row=q*4+r, col=lane&15) -> LDS -> wide reads.
  // LBAR (lgkm-only) instead of __syncthreads: global stores never drained.
  const int eb = t >> 8;            // which of the 2 staged bands
  const int erow = (t >> 4) & 15;   // row within band
  const int ecs = t & 15;           // 16 threads per row
#pragma unroll
  for (int j = 0; j < 8; ++j) {
#pragma unroll
    for (int nt = 0; nt < 4; nt++)
#pragma unroll
      for (int r = 0; r < 4; r++)
        u.E[wm][q * 4 + r][wn * 64 + nt * 16 + cl] = acc[j][nt][r];
    LBAR();
    const size_t rg = (size_t)(m_base + (eb * 8 + j) * 16 + erow);
#pragma unroll
    for (int jo = 0; jo < 4; jo++) {
      const int cc = (ecs + 16 * jo) * 4;
      float4 e = *(const float4*)&u.E[eb][erow][cc];
      if constexpr (BIAS) {
        const float4 bb = *(const float4*)(bias + n_base + cc);
        e.x += bb.x; e.y += bb.y; e.z += bb.z; e.w += bb.w;
        *(float4*)((float*)Cout + rg * NOUT + n_base + cc) = e;
      } else {
        half4 hv;
        hv[0] = (_Float16)e.x; hv[1] = (_Float16)e.y;
        hv[2] = (_Float16)e.z; hv[3] = (_Float16)e.w;
        *(half4*)((_Float16*)Cout + rg * NOUT + n_base + cc) = hv;
      }
    }
    LBAR();
  }
}

// ---------------------------------------------------------------------------
// Windowed attention: one block per (head h, window b). W=64, hd=64.
// QKV rows: token = b*64+w; cols: q=h*64+e, k=512+h*64+e, v=1024+h*64+e.
// Q/K staged in fragment order: band (16 rows) x 8 chunks; chunk (r,c) of a
// band at slot c*16 + r  ->  fragment reads are band_base + lane*16.
// ---------------------------------------------------------------------------
__global__ __launch_bounds__(256, 3) void attn_win(const _Float16* __restrict__ QKV,
                                                   _Float16* __restrict__ Out) {
  __shared__ _Float16 Qs[4096];
  __shared__ _Float16 Ks[4096];
  __shared__ _Float16 Vt[64][72];   // V transposed: Vt[e][j], padded rows
  __shared__ _Float16 Ps[64][72];   // softmax probs
  __shared__ _Float16 Os[64][72];   // output staging
  const int h = blockIdx.x, b = blockIdx.y;
  const int t = threadIdx.x;
  const int lane = t & 63, wid = t >> 6;
  const int cl = lane & 15, q = lane >> 4;

  // ---- stage Q,K (async, fragment order) and V (manual transpose) ----
  {
    // slot s -> band = s>>7 (16 rows), chunk c = (s>>4)&7, row r = s&15
    const int s0 = t, s1 = t + 256;
    const int r0 = ((s0 >> 7) << 4) | (s0 & 15), ch0 = (s0 >> 4) & 7;
    const int r1 = ((s1 >> 7) << 4) | (s1 & 15), ch1 = (s1 >> 4) & 7;
    const _Float16* g0 = QKV + (size_t)(b * 64 + r0) * 1536 + h * 64 + ch0 * 8;
    const _Float16* g1 = QKV + (size_t)(b * 64 + r1) * 1536 + h * 64 + ch1 * 8;
    GLDS16(g0,       (char*)Qs + s0 * 16);
    GLDS16(g1,       (char*)Qs + s1 * 16);
    GLDS16(g0 + 512, (char*)Ks + s0 * 16);
    GLDS16(g1 + 512, (char*)Ks + s1 * 16);

    const int vj = t & 63, vp = t >> 6;   // row j of V, 16-half chunk vp
    const _Float16* vsrc = QKV + (size_t)(b * 64 + vj) * 1536 + 1024 + h * 64 + vp * 16;
    half8 v0 = *(const half8*)vsrc;
    half8 v1 = *(const half8*)(vsrc + 8);
#pragma unroll
    for (int i = 0; i < 8; i++) Vt[vp * 16 + i][vj] = v0[i];
#pragma unroll
    for (int i = 0; i < 8; i++) Vt[vp * 16 + 8 + i][vj] = v1[i];
  }
  __syncthreads();

  const int m0 = wid * 16;      // wave's 16 query rows
  const int lane8 = lane * 8;   // fragment offset in halves within a band

  // ---- S = Q K^T ----
  f32x4 s[4] = {};
#pragma unroll
  for (int ks = 0; ks < 2; ks++) {
    half8 a = *(const half8*)(Qs + wid * 1024 + ks * 512 + lane8);
#pragma unroll
    for (int nt = 0; nt < 4; nt++) {
      half8 bb = *(const half8*)(Ks + nt * 1024 + ks * 512 + lane8);
      s[nt] = __builtin_amdgcn_mfma_f32_16x16x32_f16(a, bb, s[nt], 0, 0, 0);
    }
  }

  // ---- softmax over 64 keys per row (row=q*4+r, keys spread over cl x nt) ----
  constexpr float SC = 0.125f * 1.44269504088896340736f;  // scale * log2(e)
#pragma unroll
  for (int r = 0; r < 4; r++) {
    float mx = fmaxf(fmaxf(s[0][r], s[1][r]), fmaxf(s[2][r], s[3][r]));
    mx = fmaxf(mx, __shfl_xor(mx, 1));
    mx = fmaxf(mx, __shfl_xor(mx, 2));
    mx = fmaxf(mx, __shfl_xor(mx, 4));
    mx = fmaxf(mx, __shfl_xor(mx, 8));
    float e[4], ssum = 0.f;
#pragma unroll
    for (int nt = 0; nt < 4; nt++) { e[nt] = exp2f((s[nt][r] - mx) * SC); ssum += e[nt]; }
    ssum += __shfl_xor(ssum, 1);
    ssum += __shfl_xor(ssum, 2);
    ssum += __shfl_xor(ssum, 4);
    ssum += __shfl_xor(ssum, 8);
    float inv = 1.f / ssum;
    const int row = m0 + q * 4 + r;
#pragma unroll
    for (int nt = 0; nt < 4; nt++) Ps[row][nt * 16 + cl] = (_Float16)(e[nt] * inv);
  }
  __syncthreads();

  // ---- O = P V  (a: Ps rows; b: Vt rows = V columns; 72-pad rotates groups) ----
  f32x4 o[4] = {};
#pragma unroll
  for (int ks = 0; ks < 2; ks++) {
    half8 a = *(const half8*)&Ps[m0 + cl][ks * 32 + q * 8];
#pragma unroll
    for (int nt = 0; nt < 4; nt++) {
      half8 bb = *(const half8*)&Vt[nt * 16 + cl][ks * 32 + q * 8];
      o[nt] = __builtin_amdgcn_mfma_f32_16x16x32_f16(a, bb, o[nt], 0, 0, 0);
    }
  }
#pragma unroll
  for (int nt = 0; nt < 4; nt++)
#pragma unroll
    for (int r = 0; r < 4; r++)
      Os[m0 + q * 4 + r][nt * 16 + cl] = (_Float16)o[nt][r];
  __syncthreads();

  // ---- coalesced write-out ----
  {
    const int row = t >> 2, cs = t & 3;
    half8 h0 = *(const half8*)&Os[row][cs * 16];
    half8 h1 = *(const half8*)&Os[row][cs * 16 + 8];
    _Float16* dst = Out + (size_t)(b * 64 + row) * 512 + h * 64 + cs * 16;
    *(half8*)dst = h0;
    *((half8*)dst + 1) = h1;
  }
}

// ---------------------------------------------------------------------------
extern "C" void kernel_launch(void* const* d_in, const int* in_sizes, int n_in,
                              void* d_out, int out_size, void* d_ws, size_t ws_size,
                              hipStream_t stream) {
  const float* x      = (const float*)d_in[0];   // 16*4096*512
  const float* qkv_w  = (const float*)d_in[1];   // 1536*512
  const float* proj_w = (const float*)d_in[2];   // 512*512
  const float* proj_b = (const float*)d_in[3];   // 512
  float* out = (float*)d_out;

  char* ws = (char*)d_ws;
  _Float16* QKVh = (_Float16*)ws;                 // 65536*1536 fp16 = 201,326,592 B
  _Float16* Xh   = (_Float16*)(ws + 201326592);   // 65536*512 fp16 = 67,108,864 B
  _Float16* Outh = Xh;                            // alias: Xh dead after qkv_gemm
  _Float16* Wq   = (_Float16*)(ws + 268435456);   // 1536*512 fp16
  _Float16* Wp   = (_Float16*)(ws + 270008320);   // 512*512 fp16

  cvt_f32_f16<<<16384, 256, 0, stream>>>(x, Xh, 16 * 4096 * 512);
  cvt_f32_f16<<<384, 256, 0, stream>>>(qkv_w, Wq, 1536 * 512);
  cvt_f32_f16<<<128, 256, 0, stream>>>(proj_w, Wp, 512 * 512);
  gemm_bt<1536, 6, false><<<1536, 512, 0, stream>>>(Xh, Wq, nullptr, QKVh);
  attn_win<<<dim3(8, 1024), 256, 0, stream>>>(QKVh, Outh);
  gemm_bt<512, 2, true><<<512, 512, 0, stream>>>(Outh, Wp, proj_b, out);
}